// Round 5
// baseline (513.290 us; speedup 1.0000x reference)
//
#include <hip/hip_runtime.h>
#include <math.h>

typedef float f32x4 __attribute__((ext_vector_type(4)));
typedef float f4 __attribute__((ext_vector_type(4)));
typedef __bf16 bf16x8 __attribute__((ext_vector_type(8)));
typedef __bf16 bf16x4 __attribute__((ext_vector_type(4)));

#define GLOBAL_AS __attribute__((address_space(1)))
#define LDS_AS __attribute__((address_space(3)))

// ---------------- mask canonicalization ----------------
__global__ __launch_bounds__(256) void mask_canon(const unsigned char* __restrict__ raw,
                                                  float* __restrict__ msk, int n) {
    int i = blockIdx.x * 256 + threadIdx.x;
    if (i >= n) return;
    unsigned int w0 = *(const unsigned int*)raw;
    float v;
    if (w0 == 0x01010101u)       v = raw[i] ? 1.f : 0.f;           // bool bytes
    else if (w0 == 0x3f800000u)  v = ((const float*)raw)[i];       // float32
    else                         v = ((const int*)raw)[i] ? 1.f : 0.f; // int32
    msk[i] = v;
}

// ---------------- per-batch valid length (right-padded prefix mask) ----------------
__global__ __launch_bounds__(256) void lens_kernel(const float* __restrict__ msk,
                                                   float* __restrict__ lens) {
    int b = blockIdx.x, tid = threadIdx.x;
    float s = 0.f;
    for (int i = tid; i < 2048; i += 256) s += msk[b * 2048 + i];
#pragma unroll
    for (int off = 1; off < 64; off <<= 1) s += __shfl_xor(s, off);
    __shared__ float red[4];
    int wave = tid >> 6, lane = tid & 63;
    if (lane == 0) red[wave] = s;
    __syncthreads();
    if (tid == 0) lens[b] = red[0] + red[1] + red[2] + red[3];
}

// ---------------- transpose + f32->bf16 convert: src[K][N] -> dst[N][K] ----------------
__global__ __launch_bounds__(256) void tcvt(const float* __restrict__ src,
                                            __bf16* __restrict__ dst, int K, int N) {
    __shared__ float tile[32][33];
    int n0 = blockIdx.x * 32, k0 = blockIdx.y * 32;
    int tx = threadIdx.x & 31, ty = threadIdx.x >> 5;  // ty 0..7
#pragma unroll
    for (int i = 0; i < 4; ++i)
        tile[ty + 8 * i][tx] = src[(long)(k0 + ty + 8 * i) * N + n0 + tx];
    __syncthreads();
#pragma unroll
    for (int i = 0; i < 4; ++i)
        dst[(long)(n0 + ty + 8 * i) * K + k0 + tx] = (__bf16)tile[tx][ty + 8 * i];
}

// ---------------- LayerNorm * mask -> bf16 ----------------
__global__ __launch_bounds__(256) void ln_kernel(const float* __restrict__ x,
                                                 const float* __restrict__ w,
                                                 const float* __restrict__ bsc,
                                                 const float* __restrict__ msk,
                                                 __bf16* __restrict__ out) {
    long row = blockIdx.x;
    int tid = threadIdx.x;
    f4 xv = *(const f4*)(x + row * 1024 + tid * 4);
    float s = xv[0] + xv[1] + xv[2] + xv[3];
    float sq = xv[0] * xv[0] + xv[1] * xv[1] + xv[2] * xv[2] + xv[3] * xv[3];
#pragma unroll
    for (int off = 1; off < 64; off <<= 1) {
        s += __shfl_xor(s, off);
        sq += __shfl_xor(sq, off);
    }
    __shared__ float red[2][4];
    int wave = tid >> 6, lane = tid & 63;
    if (lane == 0) { red[0][wave] = s; red[1][wave] = sq; }
    __syncthreads();
    s = red[0][0] + red[0][1] + red[0][2] + red[0][3];
    sq = red[1][0] + red[1][1] + red[1][2] + red[1][3];
    float mu = s * (1.0f / 1024.0f);
    float var = sq * (1.0f / 1024.0f) - mu * mu;
    float rs = rsqrtf(var + 1e-5f);
    float mv = msk[row];
    f4 wv = *(const f4*)(w + tid * 4);
    f4 bv = *(const f4*)(bsc + tid * 4);
    bf16x4 ov;
#pragma unroll
    for (int j = 0; j < 4; ++j)
        ov[j] = (__bf16)(((xv[j] - mu) * rs * wv[j] + bv[j]) * mv);
    *(bf16x4*)(out + row * 1024 + tid * 4) = ov;
}

// ---------------- out = (bias + resid) * msk  (split-K accumulator pre-init) ----------------
__global__ __launch_bounds__(256) void preinit(const float* __restrict__ resid,
                                               const float* __restrict__ bias,
                                               const float* __restrict__ msk,
                                               float* __restrict__ out) {
    long i = (long)blockIdx.x * 256 + threadIdx.x;  // f4 index; grid covers 8192*256
    long row = i >> 8;                              // 256 f4 per 1024-col row
    f4 r = ((const f4*)resid)[i];
    f4 b = ((const f4*)bias)[i & 255];
    float m = msk[row];
    f4 o;
#pragma unroll
    for (int j = 0; j < 4; ++j) o[j] = (r[j] + b[j]) * m;
    ((f4*)out)[i] = o;
}

// ======== shared phase-discipline asm helpers (m201 template) ========
#define BARRIER   __asm__ volatile("s_barrier" ::: "memory")
#define LGKM0     __asm__ volatile("s_waitcnt lgkmcnt(0)" ::: "memory")
#define PRIO1     __builtin_amdgcn_s_setprio(1)
#define PRIO0     __builtin_amdgcn_s_setprio(0)

// ---------------- bf16 GEMM, 256x256 tile, m201-faithful 8-phase ----------------
// C = A[M,Ks]*B[N,Ks]^T over K columns starting at blockIdx.z*K (split-K via grid z).
// 512 thr = 8 waves (2M x 4N), per-wave C = 128x64. LDS 128 KiB, dbuf whole-tile.
// Per K-tile t (dbuf d=t&1), 4 phases, EACH = {ds_read subtile | stage 1 half ->
// barrier -> lgkmcnt(0) -> setprio(1) 16 MFMA setprio(0) -> barrier}; counted
// vmcnt(4) once per tile (B(t+2) stays in flight across the tile boundary).
// EP: 0 = store bf16; 1 = +bias,relu -> bf16; 2 = split-K: atomicAdd(out, acc*msk[row])
//     (caller pre-initializes out with (bias+resid)*msk via preinit).
template <int EP>
__global__ __launch_bounds__(512, 2) void gemm_bt8(const __bf16* __restrict__ A,
                                                   const __bf16* __restrict__ B,
                                                   int K, int Ks, int N,
                                                   void* __restrict__ Cout,
                                                   const float* __restrict__ bias,
                                                   const float* __restrict__ mskp) {
    __shared__ __bf16 As[2][2][128 * 64];
    __shared__ __bf16 Bs[2][2][128 * 64];
    int tid = threadIdx.x;
    int wave = tid >> 6, lane = tid & 63;
    int l15 = lane & 15, quad = lane >> 4;
    int r8 = l15 & 7;
    int wm = wave >> 2, wn = wave & 3;
    long rowBase = (long)blockIdx.x * 256;
    long colBase = (long)blockIdx.y * 256;
    long koff = (long)blockIdx.z * K;
    const __bf16* Ab = A + rowBase * Ks + koff;
    const __bf16* Bb = B + colBase * Ks + koff;
    int srow = lane >> 3;                 // 0..7
    int scol = ((lane & 7) ^ srow) * 8;   // pre-swizzled global col (elements)
    f32x4 acc[8][4] = {};

#define STGA(d_, h_, kt_)                                                                   \
    do {                                                                                    \
        _Pragma("unroll") for (int j = 0; j < 2; ++j) {                                     \
            const __bf16* g_ = Ab + (long)((h_) * 128 + wave * 16 + j * 8 + srow) * Ks +    \
                               (kt_) + scol;                                                \
            __builtin_amdgcn_global_load_lds(                                               \
                (const GLOBAL_AS void*)g_,                                                  \
                (LDS_AS void*)((char*)&As[d_][h_][0] + wave * 2048 + j * 1024), 16, 0, 0);  \
        }                                                                                   \
    } while (0)
#define STGB(d_, h_, kt_)                                                                   \
    do {                                                                                    \
        _Pragma("unroll") for (int j = 0; j < 2; ++j) {                                     \
            const __bf16* g_ = Bb + (long)((h_) * 128 + wave * 16 + j * 8 + srow) * Ks +    \
                               (kt_) + scol;                                                \
            __builtin_amdgcn_global_load_lds(                                               \
                (const GLOBAL_AS void*)g_,                                                  \
                (LDS_AS void*)((char*)&Bs[d_][h_][0] + wave * 2048 + j * 1024), 16, 0, 0);  \
        }                                                                                   \
    } while (0)
#define RDA(mh)                                                                      \
    do {                                                                             \
        _Pragma("unroll") for (int mi = 0; mi < 4; ++mi) {                           \
            int row_ = (mh) * 64 + mi * 16 + l15;                                    \
            af[mi][0] = *(const bf16x8*)(Ac + row_ * 64 + ((quad ^ r8) << 3));       \
            af[mi][1] = *(const bf16x8*)(Ac + row_ * 64 + (((4 + quad) ^ r8) << 3)); \
        }                                                                            \
    } while (0)
#define RDB(h)                                                                           \
    do {                                                                                 \
        _Pragma("unroll") for (int ni = 0; ni < 2; ++ni) {                               \
            int row_ = (wn & 1) * 64 + ((h) * 2 + ni) * 16 + l15;                        \
            bfr[h][ni][0] = *(const bf16x8*)(Bc + row_ * 64 + ((quad ^ r8) << 3));       \
            bfr[h][ni][1] = *(const bf16x8*)(Bc + row_ * 64 + (((4 + quad) ^ r8) << 3)); \
        }                                                                                \
    } while (0)
#define MM(mh, nh)                                                                          \
    do {                                                                                    \
        PRIO1;                                                                              \
        _Pragma("unroll") for (int mi = 0; mi < 4; ++mi) {                                  \
            _Pragma("unroll") for (int ni = 0; ni < 2; ++ni) {                              \
                acc[(mh) * 4 + mi][(nh) * 2 + ni] = __builtin_amdgcn_mfma_f32_16x16x32_bf16(\
                    af[mi][0], bfr[nh][ni][0], acc[(mh) * 4 + mi][(nh) * 2 + ni], 0, 0, 0); \
                acc[(mh) * 4 + mi][(nh) * 2 + ni] = __builtin_amdgcn_mfma_f32_16x16x32_bf16(\
                    af[mi][1], bfr[nh][ni][1], acc[(mh) * 4 + mi][(nh) * 2 + ni], 0, 0, 0); \
            }                                                                               \
        }                                                                                   \
        PRIO0;                                                                              \
    } while (0)

    const int NT = K >> 6;
    // prologue: tile 0 (A0,A1,B0,B1 -> dbuf0) + B halves of tile 1 -> dbuf1
    STGA(0, 0, 0); STGA(0, 1, 0); STGB(0, 0, 0); STGB(0, 1, 0);
    STGB(1, 0, 64); STGB(1, 1, 64);
    __asm__ volatile("s_waitcnt vmcnt(4)" ::: "memory");  // retire tile0, keep B(1)
    BARRIER;

    bf16x8 af[4][2], bfr[2][2][2];
    int kt = 0;
    for (int t = 0; t < NT; ++t, kt += 64) {
        int d = t & 1;
        const __bf16* Ac = &As[d][wm][0];
        const __bf16* Bc = &Bs[d][wn >> 1][0];
        const bool haveA1 = (t + 1 < NT), haveB2 = (t + 2 < NT);
        // ---- p1 ----
        RDA(0); RDB(0);
        if (haveA1) STGA(d ^ 1, 0, kt + 64);
        BARRIER; LGKM0;
        MM(0, 0);
        BARRIER;
        // ---- p2 ----
        RDB(1);
        if (haveA1) STGA(d ^ 1, 1, kt + 64);
        BARRIER; LGKM0;
        MM(0, 1);
        BARRIER;
        // ---- p3 ----
        RDA(1);
        if (haveB2) STGB(d, 0, kt + 128);
        BARRIER; LGKM0;
        MM(1, 1);
        BARRIER;
        // ---- p4 ----
        if (haveB2) {
            STGB(d, 1, kt + 128);
            __asm__ volatile("s_waitcnt vmcnt(4)" ::: "memory");  // retire all of t+1
        } else {
            __asm__ volatile("s_waitcnt vmcnt(0)" ::: "memory");  // tail drain
        }
        BARRIER;
        MM(1, 0);
        BARRIER;
    }
#undef STGA
#undef STGB
#undef RDA
#undef RDB
#undef MM

#pragma unroll
    for (int mi = 0; mi < 8; ++mi) {
#pragma unroll
        for (int r = 0; r < 4; ++r) {
            long gr = rowBase + wm * 128 + mi * 16 + quad * 4 + r;
            float m;
            if constexpr (EP == 2) m = mskp[gr];
#pragma unroll
            for (int ni = 0; ni < 4; ++ni) {
                long gc = colBase + wn * 64 + ni * 16 + l15;
                float v = acc[mi][ni][r];
                if constexpr (EP == 0) {
                    ((__bf16*)Cout)[gr * N + gc] = (__bf16)v;
                } else if constexpr (EP == 1) {
                    v += bias[gc];
                    v = v > 0.f ? v : 0.f;
                    ((__bf16*)Cout)[gr * N + gc] = (__bf16)v;
                } else {
                    unsafeAtomicAdd(&((float*)Cout)[gr * N + gc], v * m);
                }
            }
        }
    }
}

// ---------------- bf16 GEMM, 256x128 tile, 8-phase discipline, f32 epilogue ----------------
// (proj: K=1024, grid (32,8) = 256 blocks.) EP: 2 = +bias+resid -> f32.
template <int EP>
__global__ __launch_bounds__(512, 2) void gemm_bt8n(const __bf16* __restrict__ A,
                                                    const __bf16* __restrict__ B,
                                                    int K, int N, void* __restrict__ Cout,
                                                    const float* __restrict__ bias,
                                                    const float* __restrict__ resid,
                                                    const float* __restrict__ mskp) {
    __shared__ __bf16 As2[2][2][128 * 64];
    __shared__ __bf16 Bs2[2][2][64 * 64];
    int tid = threadIdx.x;
    int wave = tid >> 6, lane = tid & 63;
    int l15 = lane & 15, quad = lane >> 4;
    int r8 = l15 & 7;
    int wm = wave >> 1, wn = wave & 1;   // 4M x 2N
    long rowBase = (long)blockIdx.x * 256;
    long colBase = (long)blockIdx.y * 128;
    const __bf16* Ab = A + rowBase * K;
    const __bf16* Bb = B + colBase * K;
    int srow = lane >> 3;                 // 0..7
    int scol = ((lane & 7) ^ srow) * 8;   // pre-swizzled global col
    f32x4 acc[4][4] = {};

#define NSTGA(d_, h_, kt_)                                                                  \
    do {                                                                                    \
        _Pragma("unroll") for (int j = 0; j < 2; ++j) {                                     \
            const __bf16* g_ = Ab + (long)((h_) * 128 + wave * 16 + j * 8 + srow) * K +     \
                               (kt_) + scol;                                                \
            __builtin_amdgcn_global_load_lds(                                               \
                (const GLOBAL_AS void*)g_,                                                  \
                (LDS_AS void*)((char*)&As2[d_][h_][0] + wave * 2048 + j * 1024), 16, 0, 0); \
        }                                                                                   \
    } while (0)
#define NSTGB(d_, h_, kt_)                                                                  \
    do {                                                                                    \
        const __bf16* g_ = Bb + (long)((h_) * 64 + wave * 8 + srow) * K + (kt_) + scol;     \
        __builtin_amdgcn_global_load_lds(                                                   \
            (const GLOBAL_AS void*)g_,                                                      \
            (LDS_AS void*)((char*)&Bs2[d_][h_][0] + wave * 1024), 16, 0, 0);                \
    } while (0)
#define NRA(H)                                                                           \
    do {                                                                                 \
        _Pragma("unroll") for (int mi = 0; mi < 2; ++mi) {                               \
            int row_ = (wm & 1) * 64 + ((H) * 2 + mi) * 16 + l15;                        \
            afr[H][mi][0] = *(const bf16x8*)(Ac + row_ * 64 + ((quad ^ r8) << 3));       \
            afr[H][mi][1] = *(const bf16x8*)(Ac + row_ * 64 + (((4 + quad) ^ r8) << 3)); \
        }                                                                                \
    } while (0)
#define NRB(H)                                                                            \
    do {                                                                                  \
        _Pragma("unroll") for (int ni = 0; ni < 2; ++ni) {                                \
            int row_ = ((H) * 2 + ni) * 16 + l15;                                         \
            bfr2[H][ni][0] = *(const bf16x8*)(Bc + row_ * 64 + ((quad ^ r8) << 3));       \
            bfr2[H][ni][1] = *(const bf16x8*)(Bc + row_ * 64 + (((4 + quad) ^ r8) << 3)); \
        }                                                                                 \
    } while (0)
#define NMM(AH, BH)                                                                          \
    do {                                                                                     \
        PRIO1;                                                                               \
        _Pragma("unroll") for (int mi = 0; mi < 2; ++mi) {                                   \
            _Pragma("unroll") for (int ni = 0; ni < 2; ++ni) {                               \
                acc[(AH) * 2 + mi][(BH) * 2 + ni] = __builtin_amdgcn_mfma_f32_16x16x32_bf16( \
                    afr[AH][mi][0], bfr2[BH][ni][0], acc[(AH) * 2 + mi][(BH) * 2 + ni], 0,   \
                    0, 0);                                                                   \
                acc[(AH) * 2 + mi][(BH) * 2 + ni] = __builtin_amdgcn_mfma_f32_16x16x32_bf16( \
                    afr[AH][mi][1], bfr2[BH][ni][1], acc[(AH) * 2 + mi][(BH) * 2 + ni], 0,   \
                    0, 0);                                                                   \
            }                                                                                \
        }                                                                                    \
        PRIO0;                                                                               \
    } while (0)

    const int NT = K >> 6;
    NSTGA(0, 0, 0); NSTGA(0, 1, 0); NSTGB(0, 0, 0); NSTGB(0, 1, 0);
    NSTGB(1, 0, 64); NSTGB(1, 1, 64);
    __asm__ volatile("s_waitcnt vmcnt(2)" ::: "memory");
    BARRIER;

    bf16x8 afr[2][2][2], bfr2[2][2][2];
    int kt = 0;
    for (int t = 0; t < NT; ++t, kt += 64) {
        int d = t & 1;
        const __bf16* Ac = &As2[d][wm >> 1][0];
        const __bf16* Bc = &Bs2[d][wn][0];
        const bool haveA1 = (t + 1 < NT), haveB2 = (t + 2 < NT);
        NRA(0); NRB(0);
        if (haveA1) NSTGA(d ^ 1, 0, kt + 64);
        BARRIER; LGKM0;
        NMM(0, 0);
        BARRIER;
        NRB(1);
        if (haveA1) NSTGA(d ^ 1, 1, kt + 64);
        BARRIER; LGKM0;
        NMM(0, 1);
        BARRIER;
        NRA(1);
        if (haveB2) NSTGB(d, 0, kt + 128);
        BARRIER; LGKM0;
        NMM(1, 1);
        BARRIER;
        if (haveB2) {
            NSTGB(d, 1, kt + 128);
            __asm__ volatile("s_waitcnt vmcnt(2)" ::: "memory");
        } else {
            __asm__ volatile("s_waitcnt vmcnt(0)" ::: "memory");
        }
        BARRIER;
        NMM(1, 0);
        BARRIER;
    }
#undef NSTGA
#undef NSTGB
#undef NRA
#undef NRB
#undef NMM

#pragma unroll
    for (int mi = 0; mi < 4; ++mi) {
#pragma unroll
        for (int r = 0; r < 4; ++r) {
            long gr = rowBase + wm * 64 + mi * 16 + quad * 4 + r;
#pragma unroll
            for (int ni = 0; ni < 4; ++ni) {
                long gc = colBase + wn * 64 + ni * 16 + l15;
                float v = acc[mi][ni][r];
                if constexpr (EP == 2) {
                    v += bias[gc] + resid[gr * N + gc];
                    ((float*)Cout)[gr * N + gc] = v;
                } else {
                    v = (v + bias[gc] + resid[gr * N + gc]) * mskp[gr];
                    ((float*)Cout)[gr * N + gc] = v;
                }
            }
        }
    }
}

// ---------------- fused flash attention v8 ----------------
#define SWIZ(row, d) ((row) * 64 + ((((d) >> 3) ^ ((row) & 7)) << 3) + ((d) & 7))
__global__ __launch_bounds__(256, 3) void attn_kernel(const __bf16* __restrict__ qkv,
                                                      const float* __restrict__ lens,
                                                      __bf16* __restrict__ att) {
    const int T = 2048, C3 = 3072;
    int bh = blockIdx.x;           // b*16 + h
    int qt = 15 - blockIdx.y;      // heavy tiles dispatch first
    int h = bh & 15, b = bh >> 4;
    int tid = threadIdx.x;
    int wave = tid >> 6, lane = tid & 63, l15 = lane & 15, quad = lane >> 4;

    __shared__ __bf16 Kl[64 * 64];      // [key][d], swizzled
    __shared__ __bf16 Vt[64 * 64];      // [d][key], swizzled
    __shared__ __bf16 Pl[4][32 * 64];   // per-wave [q][key], swizzled

    long rowB = (long)b * T;
    const __bf16* kbase = qkv + rowB * C3 + 1024 + h * 64;
    const __bf16* vbase = qkv + rowB * C3 + 2048 + h * 64;
    const float scale2 = (1.0f / 32.0f) * 1.44269504088896f;  // C^-0.5 * log2(e)

    int krow = tid >> 2, kd = (tid & 3) * 16;       // K staging: 4 lanes/row, 32B each
    int vk = (tid & 15) * 4, vd = (tid >> 4) * 4;   // V staging: 4 keys x 4 d per thread
    int vc8 = vk >> 3, vk7 = vk & 7;                // key chunk / in-chunk offset

    bf16x8 ones;
#pragma unroll
    for (int j = 0; j < 8; ++j) ones[j] = (__bf16)1.0f;

    __bf16* pw = &Pl[wave][0];
    int r8 = l15 & 7;  // row&7 for all frag reads (row = *16 + l15)

    int qbase = qt * 128;
    int wq0 = qbase + wave * 32;  // this wave's 32 q-rows

    bf16x8 qf[2][2];
#pragma unroll
    for (int g = 0; g < 2; ++g) {
        const __bf16* qptr = qkv + (rowB + wq0 + g * 16 + l15) * C3 + h * 64;
        qf[g][0] = *(const bf16x8*)(qptr + quad * 8);
        qf[g][1] = *(const bf16x8*)(qptr + 32 + quad * 8);
    }

    f32x4 o0[4] = {}, o1[4] = {};
    f32x4 lacc0 = {}, lacc1 = {};
    int nchunk = 2 * qt + 2;
    float len = lens[b];

    bf16x8 kpre0, kpre1;
    bf16x4 vpre[4];
    {
        const __bf16* kg = kbase + (long)krow * C3 + kd;
        kpre0 = *(const bf16x8*)kg;
        kpre1 = *(const bf16x8*)(kg + 8);
#pragma unroll
        for (int j = 0; j < 4; ++j)
            vpre[j] = *(const bf16x4*)(vbase + (long)(vk + j) * C3 + vd);
    }

    for (int c = 0; c < nchunk; ++c) {
        int k0 = c * 64;
        __asm__ volatile("s_barrier" ::: "memory");
        *(bf16x8*)(&Kl[SWIZ(krow, kd)]) = kpre0;
        *(bf16x8*)(&Kl[SWIZ(krow, kd + 8)]) = kpre1;
#pragma unroll
        for (int dd = 0; dd < 4; ++dd) {
            bf16x4 w = {vpre[0][dd], vpre[1][dd], vpre[2][dd], vpre[3][dd]};
            int d = vd + dd;
            *(bf16x4*)(&Vt[d * 64 + ((vc8 ^ (d & 7)) << 3) + vk7]) = w;
        }
        if (c + 1 < nchunk) {
            int k1 = k0 + 64;
            const __bf16* kg = kbase + (long)(k1 + krow) * C3 + kd;
            kpre0 = *(const bf16x8*)kg;
            kpre1 = *(const bf16x8*)(kg + 8);
#pragma unroll
            for (int j = 0; j < 4; ++j)
                vpre[j] = *(const bf16x4*)(vbase + (long)(k1 + vk + j) * C3 + vd);
        }
        __asm__ volatile("s_waitcnt lgkmcnt(0)\n\ts_barrier" ::: "memory");

        if (k0 <= wq0 + 31) {
            f32x4 s0[4] = {}, s1[4] = {};
#pragma unroll
            for (int n = 0; n < 4; ++n) {
                int row = n * 16 + l15;
                bf16x8 kb0 = *(const bf16x8*)(&Kl[row * 64 + ((quad ^ r8) << 3)]);
                bf16x8 kb1 = *(const bf16x8*)(&Kl[row * 64 + (((4 + quad) ^ r8) << 3)]);
                s0[n] = __builtin_amdgcn_mfma_f32_16x16x32_bf16(kb0, qf[0][0], s0[n], 0, 0, 0);
                s0[n] = __builtin_amdgcn_mfma_f32_16x16x32_bf16(kb1, qf[0][1], s0[n], 0, 0, 0);
                s1[n] = __builtin_amdgcn_mfma_f32_16x16x32_bf16(kb0, qf[1][0], s1[n], 0, 0, 0);
                s1[n] = __builtin_amdgcn_mfma_f32_16x16x32_bf16(kb1, qf[1][1], s1[n], 0, 0, 0);
            }

            bool needC = (k0 + 63 > wq0);
#pragma unroll
            for (int n = 0; n < 4; ++n) {
                int c8 = n * 2 + (quad >> 1);
                int sub = (quad & 1) * 4;
                bf16x4 w0, w1;
                if (!needC) {
#pragma unroll
                    for (int r = 0; r < 4; ++r) {
                        w0[r] = (__bf16)exp2f(s0[n][r] * scale2);
                        w1[r] = (__bf16)exp2f(s1[n][r] * scale2);
                    }
                } else {
                    int kg = k0 + n * 16 + quad * 4;
                    int qg0 = wq0 + l15, qg1 = wq0 + 16 + l15;
#pragma unroll
                    for (int r = 0; r < 4; ++r) {
                        w0[r] = (kg + r <= qg0) ? (__bf16)exp2f(s0[n][r] * scale2) : (__bf16)0.f;
                        w1[r] = (kg + r <= qg1) ? (__bf16)exp2f(s1[n][r] * scale2) : (__bf16)0.f;
                    }
                }
                int wbase = l15 * 64 + ((c8 ^ r8) << 3) + sub;
                *(bf16x4*)(pw + wbase) = w0;
                *(bf16x4*)(pw + 1024 + wbase) = w1;
            }
            __asm__ volatile("s_waitcnt lgkmcnt(0)" ::: "memory");

            bf16x8 pa00 = *(const bf16x8*)(pw + l15 * 64 + ((quad ^ r8) << 3));
            bf16x8 pa01 = *(const bf16x8*)(pw + l15 * 64 + (((4 + quad) ^ r8) << 3));
            bf16x8 pa10 = *(const bf16x8*)(pw + 1024 + l15 * 64 + ((quad ^ r8) << 3));
            bf16x8 pa11 = *(const bf16x8*)(pw + 1024 + l15 * 64 + (((4 + quad) ^ r8) << 3));
#pragma unroll
            for (int nd = 0; nd < 4; ++nd) {
                int row = nd * 16 + l15;
                bf16x8 vb0 = *(const bf16x8*)(&Vt[row * 64 + ((quad ^ r8) << 3)]);
                bf16x8 vb1 = *(const bf16x8*)(&Vt[row * 64 + (((4 + quad) ^ r8) << 3)]);
                o0[nd] = __builtin_amdgcn_mfma_f32_16x16x32_bf16(pa00, vb0, o0[nd], 0, 0, 0);
                o0[nd] = __builtin_amdgcn_mfma_f32_16x16x32_bf16(pa01, vb1, o0[nd], 0, 0, 0);
                o1[nd] = __builtin_amdgcn_mfma_f32_16x16x32_bf16(pa10, vb0, o1[nd], 0, 0, 0);
                o1[nd] = __builtin_amdgcn_mfma_f32_16x16x32_bf16(pa11, vb1, o1[nd], 0, 0, 0);
            }
            lacc0 = __builtin_amdgcn_mfma_f32_16x16x32_bf16(pa00, ones, lacc0, 0, 0, 0);
            lacc0 = __builtin_amdgcn_mfma_f32_16x16x32_bf16(pa01, ones, lacc0, 0, 0, 0);
            lacc1 = __builtin_amdgcn_mfma_f32_16x16x32_bf16(pa10, ones, lacc1, 0, 0, 0);
            lacc1 = __builtin_amdgcn_mfma_f32_16x16x32_bf16(pa11, ones, lacc1, 0, 0, 0);
        }
    }

#pragma unroll
    for (int r = 0; r < 4; ++r) {
        int q0g = wq0 + quad * 4 + r;
        float inv0 = 1.0f / (lacc0[r] - fmaxf(0.f, (float)(q0g + 1) - len));
        long orow0 = rowB + q0g;
        int q1g = q0g + 16;
        float inv1 = 1.0f / (lacc1[r] - fmaxf(0.f, (float)(q1g + 1) - len));
        long orow1 = rowB + q1g;
#pragma unroll
        for (int nd = 0; nd < 4; ++nd) {
            att[orow0 * 1024 + h * 64 + nd * 16 + l15] = (__bf16)(o0[nd][r] * inv0);
            att[orow1 * 1024 + h * 64 + nd * 16 + l15] = (__bf16)(o1[nd][r] * inv1);
        }
    }
}

// ---------------- launch ----------------
extern "C" void kernel_launch(void* const* d_in, const int* in_sizes, int n_in,
                              void* d_out, int out_size, void* d_ws, size_t ws_size,
                              hipStream_t stream) {
    const float* x      = (const float*)d_in[0];
    const void*  kpm    = d_in[1];
    const float* wq     = (const float*)d_in[2];
    const float* wk     = (const float*)d_in[3];
    const float* wv     = (const float*)d_in[4];
    const float* proj_w = (const float*)d_in[5];
    const float* proj_b = (const float*)d_in[6];
    const float* ff_w1  = (const float*)d_in[7];
    const float* ff_b1  = (const float*)d_in[8];
    const float* ff_w2  = (const float*)d_in[9];
    const float* ff_b2  = (const float*)d_in[10];
    const float* ln1w   = (const float*)d_in[11];
    const float* ln1b   = (const float*)d_in[12];
    const float* ln2w   = (const float*)d_in[13];
    const float* ln2b   = (const float*)d_in[14];

    char* ws = (char*)d_ws;
    size_t off = 0;
    auto take = [&](size_t bytes) -> char* {
        char* p = ws + off;
        off += (bytes + 255) & ~(size_t)255;
        return p;
    };
    float*  msk    = (float*)take(8192 * 4);
    float*  lens   = (float*)take(256);
    __bf16* wqkvT  = (__bf16*)take(3072L * 1024 * 2);
    __bf16* wprojT = (__bf16*)take(1024L * 1024 * 2);
    __bf16* wff1T  = (__bf16*)take(4096L * 1024 * 2);
    __bf16* wff2T  = (__bf16*)take(4096L * 1024 * 2);
    __bf16* h1     = (__bf16*)take(8192L * 1024 * 2);
    char*   qkv_c  = take(8192L * 3072 * 2);
    __bf16* qkvb   = (__bf16*)qkv_c;
    __bf16* attb   = (__bf16*)take(8192L * 1024 * 2);
    float*  x2     = (float*)take(8192L * 1024 * 4);
    __bf16* h2     = (__bf16*)take(8192L * 1024 * 2);
    __bf16* ffh    = (__bf16*)qkv_c;  // alias: qkv region dead after proj GEMM

    mask_canon<<<32, 256, 0, stream>>>((const unsigned char*)kpm, msk, 8192);
    lens_kernel<<<4, 256, 0, stream>>>(msk, lens);
    tcvt<<<dim3(32, 32), 256, 0, stream>>>(wq, wqkvT, 1024, 1024);
    tcvt<<<dim3(32, 32), 256, 0, stream>>>(wk, wqkvT + 1024L * 1024, 1024, 1024);
    tcvt<<<dim3(32, 32), 256, 0, stream>>>(wv, wqkvT + 2048L * 1024, 1024, 1024);
    tcvt<<<dim3(32, 32), 256, 0, stream>>>(proj_w, wprojT, 1024, 1024);
    tcvt<<<dim3(128, 32), 256, 0, stream>>>(ff_w1, wff1T, 1024, 4096);
    tcvt<<<dim3(32, 128), 256, 0, stream>>>(ff_w2, wff2T, 4096, 1024);

    ln_kernel<<<8192, 256, 0, stream>>>(x, ln1w, ln1b, msk, h1);
    gemm_bt8<0><<<dim3(32, 12), 512, 0, stream>>>(h1, wqkvT, 1024, 1024, 3072, qkvb, nullptr, nullptr);
    attn_kernel<<<dim3(64, 16), 256, 0, stream>>>(qkvb, lens, attb);
    gemm_bt8n<2><<<dim3(32, 8), 512, 0, stream>>>(attb, wprojT, 1024, 1024, x2, proj_b, x, nullptr);
    ln_kernel<<<8192, 256, 0, stream>>>(x2, ln2w, ln2b, msk, h2);
    gemm_bt8<1><<<dim3(32, 16), 512, 0, stream>>>(h2, wff1T, 1024, 1024, 4096, ffh, ff_b1, nullptr);
    // ff2 split-K x2: out pre-initialized with (b2 + x2)*msk, halves atomicAdd p_z*msk
    preinit<<<8192, 256, 0, stream>>>(x2, ff_b2, msk, (float*)d_out);
    gemm_bt8<2><<<dim3(32, 4, 2), 512, 0, stream>>>(ffh, wff2T, 2048, 4096, 1024, (float*)d_out, nullptr, msk);
}

// Round 6
// 490.779 us; speedup vs baseline: 1.0459x; 1.0459x over previous
//
#include <hip/hip_runtime.h>
#include <math.h>

typedef float f32x4 __attribute__((ext_vector_type(4)));
typedef float f4 __attribute__((ext_vector_type(4)));
typedef __bf16 bf16x8 __attribute__((ext_vector_type(8)));
typedef __bf16 bf16x4 __attribute__((ext_vector_type(4)));

#define GLOBAL_AS __attribute__((address_space(1)))
#define LDS_AS __attribute__((address_space(3)))

// ---------------- mask canonicalization ----------------
__global__ __launch_bounds__(256) void mask_canon(const unsigned char* __restrict__ raw,
                                                  float* __restrict__ msk, int n) {
    int i = blockIdx.x * 256 + threadIdx.x;
    if (i >= n) return;
    unsigned int w0 = *(const unsigned int*)raw;
    float v;
    if (w0 == 0x01010101u)       v = raw[i] ? 1.f : 0.f;           // bool bytes
    else if (w0 == 0x3f800000u)  v = ((const float*)raw)[i];       // float32
    else                         v = ((const int*)raw)[i] ? 1.f : 0.f; // int32
    msk[i] = v;
}

// ---------------- per-batch valid length (right-padded prefix mask) ----------------
__global__ __launch_bounds__(256) void lens_kernel(const float* __restrict__ msk,
                                                   float* __restrict__ lens) {
    int b = blockIdx.x, tid = threadIdx.x;
    float s = 0.f;
    for (int i = tid; i < 2048; i += 256) s += msk[b * 2048 + i];
#pragma unroll
    for (int off = 1; off < 64; off <<= 1) s += __shfl_xor(s, off);
    __shared__ float red[4];
    int wave = tid >> 6, lane = tid & 63;
    if (lane == 0) red[wave] = s;
    __syncthreads();
    if (tid == 0) lens[b] = red[0] + red[1] + red[2] + red[3];
}

// ---------------- transpose + f32->bf16 convert: src[K][N] -> dst[N][K] ----------------
__global__ __launch_bounds__(256) void tcvt(const float* __restrict__ src,
                                            __bf16* __restrict__ dst, int K, int N) {
    __shared__ float tile[32][33];
    int n0 = blockIdx.x * 32, k0 = blockIdx.y * 32;
    int tx = threadIdx.x & 31, ty = threadIdx.x >> 5;  // ty 0..7
#pragma unroll
    for (int i = 0; i < 4; ++i)
        tile[ty + 8 * i][tx] = src[(long)(k0 + ty + 8 * i) * N + n0 + tx];
    __syncthreads();
#pragma unroll
    for (int i = 0; i < 4; ++i)
        dst[(long)(n0 + ty + 8 * i) * K + k0 + tx] = (__bf16)tile[tx][ty + 8 * i];
}

// ---------------- LayerNorm * mask -> bf16 ----------------
__global__ __launch_bounds__(256) void ln_kernel(const float* __restrict__ x,
                                                 const float* __restrict__ w,
                                                 const float* __restrict__ bsc,
                                                 const float* __restrict__ msk,
                                                 __bf16* __restrict__ out) {
    long row = blockIdx.x;
    int tid = threadIdx.x;
    f4 xv = *(const f4*)(x + row * 1024 + tid * 4);
    float s = xv[0] + xv[1] + xv[2] + xv[3];
    float sq = xv[0] * xv[0] + xv[1] * xv[1] + xv[2] * xv[2] + xv[3] * xv[3];
#pragma unroll
    for (int off = 1; off < 64; off <<= 1) {
        s += __shfl_xor(s, off);
        sq += __shfl_xor(sq, off);
    }
    __shared__ float red[2][4];
    int wave = tid >> 6, lane = tid & 63;
    if (lane == 0) { red[0][wave] = s; red[1][wave] = sq; }
    __syncthreads();
    s = red[0][0] + red[0][1] + red[0][2] + red[0][3];
    sq = red[1][0] + red[1][1] + red[1][2] + red[1][3];
    float mu = s * (1.0f / 1024.0f);
    float var = sq * (1.0f / 1024.0f) - mu * mu;
    float rs = rsqrtf(var + 1e-5f);
    float mv = msk[row];
    f4 wv = *(const f4*)(w + tid * 4);
    f4 bv = *(const f4*)(bsc + tid * 4);
    bf16x4 ov;
#pragma unroll
    for (int j = 0; j < 4; ++j)
        ov[j] = (__bf16)(((xv[j] - mu) * rs * wv[j] + bv[j]) * mv);
    *(bf16x4*)(out + row * 1024 + tid * 4) = ov;
}

// ======== shared phase-discipline asm helpers (m201 template) ========
#define BARRIER   __asm__ volatile("s_barrier" ::: "memory")
#define LGKM0     __asm__ volatile("s_waitcnt lgkmcnt(0)" ::: "memory")
#define PRIO1     __builtin_amdgcn_s_setprio(1)
#define PRIO0     __builtin_amdgcn_s_setprio(0)

// bijective XCD swizzle (valid when nwg%8==0): dispatch id (x-fastest, id%8 ~ XCD)
// -> logical id in col-fastest chunks, so the col-blocks that re-read the SAME
// A row-panel land on one XCD's L2 (A re-read is the dominant staged traffic).
#define XCD_SWIZZLE(BX, BY)                                          \
    int BX, BY;                                                      \
    {                                                                \
        int id_ = blockIdx.x + gridDim.x * blockIdx.y;               \
        int nwg_ = gridDim.x * gridDim.y;                            \
        int l_ = (id_ & 7) * (nwg_ >> 3) + (id_ >> 3);               \
        BX = l_ / gridDim.y;                                         \
        BY = l_ % gridDim.y;                                         \
    }

// ---------------- bf16 GEMM, 256x256 tile, m201-faithful 8-phase ----------------
// C = A[M,K]*B[N,K]^T. 512 thr = 8 waves (2M x 4N), per-wave C = 128x64.
// LDS [2 dbuf][2 half][128x64] per operand = 128 KiB. Half-tile = 128 rows = 16 KB
// = 2 global_load_lds per thread. Swizzle: slot s of row r holds col-chunk s^(r&7)
// (linear DMA dest + pre-swizzled global col; ds_read slot quad^r8 -> 0 conflicts).
// Per K-tile t (dbuf d=t&1), 4 phases, EACH = {ds_read subtile | stage 1 half ->
// barrier -> lgkmcnt(0) -> setprio(1) 16 MFMA setprio(0) -> barrier}; counted
// vmcnt(4) once per tile (B(t+2) stays in flight across the tile boundary).
// EP: 0 = store bf16; 1 = +bias,relu -> bf16.
template <int EP>
__global__ __launch_bounds__(512, 2) void gemm_bt8(const __bf16* __restrict__ A,
                                                   const __bf16* __restrict__ B,
                                                   int K, int N, void* __restrict__ Cout,
                                                   const float* __restrict__ bias) {
    __shared__ __bf16 As[2][2][128 * 64];
    __shared__ __bf16 Bs[2][2][128 * 64];
    int tid = threadIdx.x;
    int wave = tid >> 6, lane = tid & 63;
    int l15 = lane & 15, quad = lane >> 4;
    int r8 = l15 & 7;
    int wm = wave >> 2, wn = wave & 3;
    XCD_SWIZZLE(bx, by);
    long rowBase = (long)bx * 256;
    long colBase = (long)by * 256;
    const __bf16* Ab = A + rowBase * K;
    const __bf16* Bb = B + colBase * K;
    int srow = lane >> 3;                 // 0..7
    int scol = ((lane & 7) ^ srow) * 8;   // pre-swizzled global col (elements)
    f32x4 acc[8][4] = {};

#define STGA(d_, h_, kt_)                                                                   \
    do {                                                                                    \
        _Pragma("unroll") for (int j = 0; j < 2; ++j) {                                     \
            const __bf16* g_ = Ab + (long)((h_) * 128 + wave * 16 + j * 8 + srow) * K +     \
                               (kt_) + scol;                                                \
            __builtin_amdgcn_global_load_lds(                                               \
                (const GLOBAL_AS void*)g_,                                                  \
                (LDS_AS void*)((char*)&As[d_][h_][0] + wave * 2048 + j * 1024), 16, 0, 0);  \
        }                                                                                   \
    } while (0)
#define STGB(d_, h_, kt_)                                                                   \
    do {                                                                                    \
        _Pragma("unroll") for (int j = 0; j < 2; ++j) {                                     \
            const __bf16* g_ = Bb + (long)((h_) * 128 + wave * 16 + j * 8 + srow) * K +     \
                               (kt_) + scol;                                                \
            __builtin_amdgcn_global_load_lds(                                               \
                (const GLOBAL_AS void*)g_,                                                  \
                (LDS_AS void*)((char*)&Bs[d_][h_][0] + wave * 2048 + j * 1024), 16, 0, 0);  \
        }                                                                                   \
    } while (0)
#define RDA(mh)                                                                      \
    do {                                                                             \
        _Pragma("unroll") for (int mi = 0; mi < 4; ++mi) {                           \
            int row_ = (mh) * 64 + mi * 16 + l15;                                    \
            af[mi][0] = *(const bf16x8*)(Ac + row_ * 64 + ((quad ^ r8) << 3));       \
            af[mi][1] = *(const bf16x8*)(Ac + row_ * 64 + (((4 + quad) ^ r8) << 3)); \
        }                                                                            \
    } while (0)
#define RDB(h)                                                                           \
    do {                                                                                 \
        _Pragma("unroll") for (int ni = 0; ni < 2; ++ni) {                               \
            int row_ = (wn & 1) * 64 + ((h) * 2 + ni) * 16 + l15;                        \
            bfr[h][ni][0] = *(const bf16x8*)(Bc + row_ * 64 + ((quad ^ r8) << 3));       \
            bfr[h][ni][1] = *(const bf16x8*)(Bc + row_ * 64 + (((4 + quad) ^ r8) << 3)); \
        }                                                                                \
    } while (0)
#define MM(mh, nh)                                                                          \
    do {                                                                                    \
        PRIO1;                                                                              \
        _Pragma("unroll") for (int mi = 0; mi < 4; ++mi) {                                  \
            _Pragma("unroll") for (int ni = 0; ni < 2; ++ni) {                              \
                acc[(mh) * 4 + mi][(nh) * 2 + ni] = __builtin_amdgcn_mfma_f32_16x16x32_bf16(\
                    af[mi][0], bfr[nh][ni][0], acc[(mh) * 4 + mi][(nh) * 2 + ni], 0, 0, 0); \
                acc[(mh) * 4 + mi][(nh) * 2 + ni] = __builtin_amdgcn_mfma_f32_16x16x32_bf16(\
                    af[mi][1], bfr[nh][ni][1], acc[(mh) * 4 + mi][(nh) * 2 + ni], 0, 0, 0); \
            }                                                                               \
        }                                                                                   \
        PRIO0;                                                                              \
    } while (0)

    const int NT = K >> 6;
    // prologue: tile 0 (A0,A1,B0,B1 -> dbuf0) + B halves of tile 1 -> dbuf1
    STGA(0, 0, 0); STGA(0, 1, 0); STGB(0, 0, 0); STGB(0, 1, 0);
    STGB(1, 0, 64); STGB(1, 1, 64);
    __asm__ volatile("s_waitcnt vmcnt(4)" ::: "memory");  // retire tile0, keep B(1)
    BARRIER;

    bf16x8 af[4][2], bfr[2][2][2];
    int kt = 0;
    for (int t = 0; t < NT; ++t, kt += 64) {
        int d = t & 1;
        const __bf16* Ac = &As[d][wm][0];
        const __bf16* Bc = &Bs[d][wn >> 1][0];
        const bool haveA1 = (t + 1 < NT), haveB2 = (t + 2 < NT);
        // ---- p1 ----
        RDA(0); RDB(0);
        if (haveA1) STGA(d ^ 1, 0, kt + 64);
        BARRIER; LGKM0;
        MM(0, 0);
        BARRIER;
        // ---- p2 ----
        RDB(1);
        if (haveA1) STGA(d ^ 1, 1, kt + 64);
        BARRIER; LGKM0;
        MM(0, 1);
        BARRIER;
        // ---- p3 ----
        RDA(1);
        if (haveB2) STGB(d, 0, kt + 128);
        BARRIER; LGKM0;
        MM(1, 1);
        BARRIER;
        // ---- p4 ----
        if (haveB2) {
            STGB(d, 1, kt + 128);
            __asm__ volatile("s_waitcnt vmcnt(4)" ::: "memory");  // retire all of t+1
        } else {
            __asm__ volatile("s_waitcnt vmcnt(0)" ::: "memory");  // tail drain
        }
        BARRIER;
        MM(1, 0);
        BARRIER;
    }
#undef STGA
#undef STGB
#undef RDA
#undef RDB
#undef MM

#pragma unroll
    for (int mi = 0; mi < 8; ++mi) {
#pragma unroll
        for (int r = 0; r < 4; ++r) {
            long gr = rowBase + wm * 128 + mi * 16 + quad * 4 + r;
#pragma unroll
            for (int ni = 0; ni < 4; ++ni) {
                long gc = colBase + wn * 64 + ni * 16 + l15;
                float v = acc[mi][ni][r];
                if constexpr (EP == 0) {
                    ((__bf16*)Cout)[gr * N + gc] = (__bf16)v;
                } else {
                    v += bias[gc];
                    v = v > 0.f ? v : 0.f;
                    ((__bf16*)Cout)[gr * N + gc] = (__bf16)v;
                }
            }
        }
    }
}

// ---------------- bf16 GEMM, 256x128 tile, 8-phase discipline, f32 epilogue ----------------
// For N=1024 outputs (proj, ff2): grid (32,8) = 256 blocks = 1/CU.
// EP: 2 = +bias+resid -> f32; 3 = (+bias+resid)*msk[row] -> f32.
template <int EP>
__global__ __launch_bounds__(512, 2) void gemm_bt8n(const __bf16* __restrict__ A,
                                                    const __bf16* __restrict__ B,
                                                    int K, int N, void* __restrict__ Cout,
                                                    const float* __restrict__ bias,
                                                    const float* __restrict__ resid,
                                                    const float* __restrict__ mskp) {
    __shared__ __bf16 As2[2][2][128 * 64];
    __shared__ __bf16 Bs2[2][2][64 * 64];
    int tid = threadIdx.x;
    int wave = tid >> 6, lane = tid & 63;
    int l15 = lane & 15, quad = lane >> 4;
    int r8 = l15 & 7;
    int wm = wave >> 1, wn = wave & 1;   // 4M x 2N
    XCD_SWIZZLE(bx, by);
    long rowBase = (long)bx * 256;
    long colBase = (long)by * 128;
    const __bf16* Ab = A + rowBase * K;
    const __bf16* Bb = B + colBase * K;
    int srow = lane >> 3;                 // 0..7
    int scol = ((lane & 7) ^ srow) * 8;   // pre-swizzled global col
    f32x4 acc[4][4] = {};

#define NSTGA(d_, h_, kt_)                                                                  \
    do {                                                                                    \
        _Pragma("unroll") for (int j = 0; j < 2; ++j) {                                     \
            const __bf16* g_ = Ab + (long)((h_) * 128 + wave * 16 + j * 8 + srow) * K +     \
                               (kt_) + scol;                                                \
            __builtin_amdgcn_global_load_lds(                                               \
                (const GLOBAL_AS void*)g_,                                                  \
                (LDS_AS void*)((char*)&As2[d_][h_][0] + wave * 2048 + j * 1024), 16, 0, 0); \
        }                                                                                   \
    } while (0)
#define NSTGB(d_, h_, kt_)                                                                  \
    do {                                                                                    \
        const __bf16* g_ = Bb + (long)((h_) * 64 + wave * 8 + srow) * K + (kt_) + scol;     \
        __builtin_amdgcn_global_load_lds(                                                   \
            (const GLOBAL_AS void*)g_,                                                      \
            (LDS_AS void*)((char*)&Bs2[d_][h_][0] + wave * 1024), 16, 0, 0);                \
    } while (0)
#define NRA(H)                                                                           \
    do {                                                                                 \
        _Pragma("unroll") for (int mi = 0; mi < 2; ++mi) {                               \
            int row_ = (wm & 1) * 64 + ((H) * 2 + mi) * 16 + l15;                        \
            afr[H][mi][0] = *(const bf16x8*)(Ac + row_ * 64 + ((quad ^ r8) << 3));       \
            afr[H][mi][1] = *(const bf16x8*)(Ac + row_ * 64 + (((4 + quad) ^ r8) << 3)); \
        }                                                                                \
    } while (0)
#define NRB(H)                                                                            \
    do {                                                                                  \
        _Pragma("unroll") for (int ni = 0; ni < 2; ++ni) {                                \
            int row_ = ((H) * 2 + ni) * 16 + l15;                                         \
            bfr2[H][ni][0] = *(const bf16x8*)(Bc + row_ * 64 + ((quad ^ r8) << 3));       \
            bfr2[H][ni][1] = *(const bf16x8*)(Bc + row_ * 64 + (((4 + quad) ^ r8) << 3)); \
        }                                                                                 \
    } while (0)
#define NMM(AH, BH)                                                                          \
    do {                                                                                     \
        PRIO1;                                                                               \
        _Pragma("unroll") for (int mi = 0; mi < 2; ++mi) {                                   \
            _Pragma("unroll") for (int ni = 0; ni < 2; ++ni) {                               \
                acc[(AH) * 2 + mi][(BH) * 2 + ni] = __builtin_amdgcn_mfma_f32_16x16x32_bf16( \
                    afr[AH][mi][0], bfr2[BH][ni][0], acc[(AH) * 2 + mi][(BH) * 2 + ni], 0,   \
                    0, 0);                                                                   \
                acc[(AH) * 2 + mi][(BH) * 2 + ni] = __builtin_amdgcn_mfma_f32_16x16x32_bf16( \
                    afr[AH][mi][1], bfr2[BH][ni][1], acc[(AH) * 2 + mi][(BH) * 2 + ni], 0,   \
                    0, 0);                                                                   \
            }                                                                                \
        }                                                                                    \
        PRIO0;                                                                               \
    } while (0)

    const int NT = K >> 6;
    NSTGA(0, 0, 0); NSTGA(0, 1, 0); NSTGB(0, 0, 0); NSTGB(0, 1, 0);
    NSTGB(1, 0, 64); NSTGB(1, 1, 64);
    __asm__ volatile("s_waitcnt vmcnt(2)" ::: "memory");
    BARRIER;

    bf16x8 afr[2][2][2], bfr2[2][2][2];
    int kt = 0;
    for (int t = 0; t < NT; ++t, kt += 64) {
        int d = t & 1;
        const __bf16* Ac = &As2[d][wm >> 1][0];
        const __bf16* Bc = &Bs2[d][wn][0];
        const bool haveA1 = (t + 1 < NT), haveB2 = (t + 2 < NT);
        NRA(0); NRB(0);
        if (haveA1) NSTGA(d ^ 1, 0, kt + 64);
        BARRIER; LGKM0;
        NMM(0, 0);
        BARRIER;
        NRB(1);
        if (haveA1) NSTGA(d ^ 1, 1, kt + 64);
        BARRIER; LGKM0;
        NMM(0, 1);
        BARRIER;
        NRA(1);
        if (haveB2) NSTGB(d, 0, kt + 128);
        BARRIER; LGKM0;
        NMM(1, 1);
        BARRIER;
        if (haveB2) {
            NSTGB(d, 1, kt + 128);
            __asm__ volatile("s_waitcnt vmcnt(2)" ::: "memory");
        } else {
            __asm__ volatile("s_waitcnt vmcnt(0)" ::: "memory");
        }
        BARRIER;
        NMM(1, 0);
        BARRIER;
    }
#undef NSTGA
#undef NSTGB
#undef NRA
#undef NRB
#undef NMM

#pragma unroll
    for (int mi = 0; mi < 4; ++mi) {
#pragma unroll
        for (int r = 0; r < 4; ++r) {
            long gr = rowBase + wm * 64 + mi * 16 + quad * 4 + r;
#pragma unroll
            for (int ni = 0; ni < 4; ++ni) {
                long gc = colBase + wn * 64 + ni * 16 + l15;
                float v = acc[mi][ni][r];
                if constexpr (EP == 2) {
                    v += bias[gc] + resid[gr * N + gc];
                    ((float*)Cout)[gr * N + gc] = v;
                } else {
                    v = (v + bias[gc] + resid[gr * N + gc]) * mskp[gr];
                    ((float*)Cout)[gr * N + gc] = v;
                }
            }
        }
    }
}

// ---------------- fused flash attention v8 ----------------
#define SWIZ(row, d) ((row) * 64 + ((((d) >> 3) ^ ((row) & 7)) << 3) + ((d) & 7))
__global__ __launch_bounds__(256, 3) void attn_kernel(const __bf16* __restrict__ qkv,
                                                      const float* __restrict__ lens,
                                                      __bf16* __restrict__ att) {
    const int T = 2048, C3 = 3072;
    int bh = blockIdx.x;           // b*16 + h
    int qt = 15 - blockIdx.y;      // heavy tiles dispatch first
    int h = bh & 15, b = bh >> 4;
    int tid = threadIdx.x;
    int wave = tid >> 6, lane = tid & 63, l15 = lane & 15, quad = lane >> 4;

    __shared__ __bf16 Kl[64 * 64];      // [key][d], swizzled
    __shared__ __bf16 Vt[64 * 64];      // [d][key], swizzled
    __shared__ __bf16 Pl[4][32 * 64];   // per-wave [q][key], swizzled

    long rowB = (long)b * T;
    const __bf16* kbase = qkv + rowB * C3 + 1024 + h * 64;
    const __bf16* vbase = qkv + rowB * C3 + 2048 + h * 64;
    const float scale2 = (1.0f / 32.0f) * 1.44269504088896f;  // C^-0.5 * log2(e)

    int krow = tid >> 2, kd = (tid & 3) * 16;       // K staging: 4 lanes/row, 32B each
    int vk = (tid & 15) * 4, vd = (tid >> 4) * 4;   // V staging: 4 keys x 4 d per thread
    int vc8 = vk >> 3, vk7 = vk & 7;                // key chunk / in-chunk offset

    bf16x8 ones;
#pragma unroll
    for (int j = 0; j < 8; ++j) ones[j] = (__bf16)1.0f;

    __bf16* pw = &Pl[wave][0];
    int r8 = l15 & 7;  // row&7 for all frag reads (row = *16 + l15)

    int qbase = qt * 128;
    int wq0 = qbase + wave * 32;  // this wave's 32 q-rows

    bf16x8 qf[2][2];
#pragma unroll
    for (int g = 0; g < 2; ++g) {
        const __bf16* qptr = qkv + (rowB + wq0 + g * 16 + l15) * C3 + h * 64;
        qf[g][0] = *(const bf16x8*)(qptr + quad * 8);
        qf[g][1] = *(const bf16x8*)(qptr + 32 + quad * 8);
    }

    f32x4 o0[4] = {}, o1[4] = {};
    f32x4 lacc0 = {}, lacc1 = {};
    int nchunk = 2 * qt + 2;
    float len = lens[b];

    bf16x8 kpre0, kpre1;
    bf16x4 vpre[4];
    {
        const __bf16* kg = kbase + (long)krow * C3 + kd;
        kpre0 = *(const bf16x8*)kg;
        kpre1 = *(const bf16x8*)(kg + 8);
#pragma unroll
        for (int j = 0; j < 4; ++j)
            vpre[j] = *(const bf16x4*)(vbase + (long)(vk + j) * C3 + vd);
    }

    for (int c = 0; c < nchunk; ++c) {
        int k0 = c * 64;
        __asm__ volatile("s_barrier" ::: "memory");
        *(bf16x8*)(&Kl[SWIZ(krow, kd)]) = kpre0;
        *(bf16x8*)(&Kl[SWIZ(krow, kd + 8)]) = kpre1;
#pragma unroll
        for (int dd = 0; dd < 4; ++dd) {
            bf16x4 w = {vpre[0][dd], vpre[1][dd], vpre[2][dd], vpre[3][dd]};
            int d = vd + dd;
            *(bf16x4*)(&Vt[d * 64 + ((vc8 ^ (d & 7)) << 3) + vk7]) = w;
        }
        if (c + 1 < nchunk) {
            int k1 = k0 + 64;
            const __bf16* kg = kbase + (long)(k1 + krow) * C3 + kd;
            kpre0 = *(const bf16x8*)kg;
            kpre1 = *(const bf16x8*)(kg + 8);
#pragma unroll
            for (int j = 0; j < 4; ++j)
                vpre[j] = *(const bf16x4*)(vbase + (long)(k1 + vk + j) * C3 + vd);
        }
        __asm__ volatile("s_waitcnt lgkmcnt(0)\n\ts_barrier" ::: "memory");

        if (k0 <= wq0 + 31) {
            f32x4 s0[4] = {}, s1[4] = {};
#pragma unroll
            for (int n = 0; n < 4; ++n) {
                int row = n * 16 + l15;
                bf16x8 kb0 = *(const bf16x8*)(&Kl[row * 64 + ((quad ^ r8) << 3)]);
                bf16x8 kb1 = *(const bf16x8*)(&Kl[row * 64 + (((4 + quad) ^ r8) << 3)]);
                s0[n] = __builtin_amdgcn_mfma_f32_16x16x32_bf16(kb0, qf[0][0], s0[n], 0, 0, 0);
                s0[n] = __builtin_amdgcn_mfma_f32_16x16x32_bf16(kb1, qf[0][1], s0[n], 0, 0, 0);
                s1[n] = __builtin_amdgcn_mfma_f32_16x16x32_bf16(kb0, qf[1][0], s1[n], 0, 0, 0);
                s1[n] = __builtin_amdgcn_mfma_f32_16x16x32_bf16(kb1, qf[1][1], s1[n], 0, 0, 0);
            }

            bool needC = (k0 + 63 > wq0);
#pragma unroll
            for (int n = 0; n < 4; ++n) {
                int c8 = n * 2 + (quad >> 1);
                int sub = (quad & 1) * 4;
                bf16x4 w0, w1;
                if (!needC) {
#pragma unroll
                    for (int r = 0; r < 4; ++r) {
                        w0[r] = (__bf16)exp2f(s0[n][r] * scale2);
                        w1[r] = (__bf16)exp2f(s1[n][r] * scale2);
                    }
                } else {
                    int kg = k0 + n * 16 + quad * 4;
                    int qg0 = wq0 + l15, qg1 = wq0 + 16 + l15;
#pragma unroll
                    for (int r = 0; r < 4; ++r) {
                        w0[r] = (kg + r <= qg0) ? (__bf16)exp2f(s0[n][r] * scale2) : (__bf16)0.f;
                        w1[r] = (kg + r <= qg1) ? (__bf16)exp2f(s1[n][r] * scale2) : (__bf16)0.f;
                    }
                }
                int wbase = l15 * 64 + ((c8 ^ r8) << 3) + sub;
                *(bf16x4*)(pw + wbase) = w0;
                *(bf16x4*)(pw + 1024 + wbase) = w1;
            }
            __asm__ volatile("s_waitcnt lgkmcnt(0)" ::: "memory");

            bf16x8 pa00 = *(const bf16x8*)(pw + l15 * 64 + ((quad ^ r8) << 3));
            bf16x8 pa01 = *(const bf16x8*)(pw + l15 * 64 + (((4 + quad) ^ r8) << 3));
            bf16x8 pa10 = *(const bf16x8*)(pw + 1024 + l15 * 64 + ((quad ^ r8) << 3));
            bf16x8 pa11 = *(const bf16x8*)(pw + 1024 + l15 * 64 + (((4 + quad) ^ r8) << 3));
#pragma unroll
            for (int nd = 0; nd < 4; ++nd) {
                int row = nd * 16 + l15;
                bf16x8 vb0 = *(const bf16x8*)(&Vt[row * 64 + ((quad ^ r8) << 3)]);
                bf16x8 vb1 = *(const bf16x8*)(&Vt[row * 64 + (((4 + quad) ^ r8) << 3)]);
                o0[nd] = __builtin_amdgcn_mfma_f32_16x16x32_bf16(pa00, vb0, o0[nd], 0, 0, 0);
                o0[nd] = __builtin_amdgcn_mfma_f32_16x16x32_bf16(pa01, vb1, o0[nd], 0, 0, 0);
                o1[nd] = __builtin_amdgcn_mfma_f32_16x16x32_bf16(pa10, vb0, o1[nd], 0, 0, 0);
                o1[nd] = __builtin_amdgcn_mfma_f32_16x16x32_bf16(pa11, vb1, o1[nd], 0, 0, 0);
            }
            lacc0 = __builtin_amdgcn_mfma_f32_16x16x32_bf16(pa00, ones, lacc0, 0, 0, 0);
            lacc0 = __builtin_amdgcn_mfma_f32_16x16x32_bf16(pa01, ones, lacc0, 0, 0, 0);
            lacc1 = __builtin_amdgcn_mfma_f32_16x16x32_bf16(pa10, ones, lacc1, 0, 0, 0);
            lacc1 = __builtin_amdgcn_mfma_f32_16x16x32_bf16(pa11, ones, lacc1, 0, 0, 0);
        }
    }

#pragma unroll
    for (int r = 0; r < 4; ++r) {
        int q0g = wq0 + quad * 4 + r;
        float inv0 = 1.0f / (lacc0[r] - fmaxf(0.f, (float)(q0g + 1) - len));
        long orow0 = rowB + q0g;
        int q1g = q0g + 16;
        float inv1 = 1.0f / (lacc1[r] - fmaxf(0.f, (float)(q1g + 1) - len));
        long orow1 = rowB + q1g;
#pragma unroll
        for (int nd = 0; nd < 4; ++nd) {
            att[orow0 * 1024 + h * 64 + nd * 16 + l15] = (__bf16)(o0[nd][r] * inv0);
            att[orow1 * 1024 + h * 64 + nd * 16 + l15] = (__bf16)(o1[nd][r] * inv1);
        }
    }
}

// ---------------- launch ----------------
extern "C" void kernel_launch(void* const* d_in, const int* in_sizes, int n_in,
                              void* d_out, int out_size, void* d_ws, size_t ws_size,
                              hipStream_t stream) {
    const float* x      = (const float*)d_in[0];
    const void*  kpm    = d_in[1];
    const float* wq     = (const float*)d_in[2];
    const float* wk     = (const float*)d_in[3];
    const float* wv     = (const float*)d_in[4];
    const float* proj_w = (const float*)d_in[5];
    const float* proj_b = (const float*)d_in[6];
    const float* ff_w1  = (const float*)d_in[7];
    const float* ff_b1  = (const float*)d_in[8];
    const float* ff_w2  = (const float*)d_in[9];
    const float* ff_b2  = (const float*)d_in[10];
    const float* ln1w   = (const float*)d_in[11];
    const float* ln1b   = (const float*)d_in[12];
    const float* ln2w   = (const float*)d_in[13];
    const float* ln2b   = (const float*)d_in[14];

    char* ws = (char*)d_ws;
    size_t off = 0;
    auto take = [&](size_t bytes) -> char* {
        char* p = ws + off;
        off += (bytes + 255) & ~(size_t)255;
        return p;
    };
    float*  msk    = (float*)take(8192 * 4);
    float*  lens   = (float*)take(256);
    __bf16* wqkvT  = (__bf16*)take(3072L * 1024 * 2);
    __bf16* wprojT = (__bf16*)take(1024L * 1024 * 2);
    __bf16* wff1T  = (__bf16*)take(4096L * 1024 * 2);
    __bf16* wff2T  = (__bf16*)take(4096L * 1024 * 2);
    __bf16* h1     = (__bf16*)take(8192L * 1024 * 2);
    char*   qkv_c  = take(8192L * 3072 * 2);
    __bf16* qkvb   = (__bf16*)qkv_c;
    __bf16* attb   = (__bf16*)take(8192L * 1024 * 2);
    float*  x2     = (float*)take(8192L * 1024 * 4);
    __bf16* h2     = (__bf16*)take(8192L * 1024 * 2);
    __bf16* ffh    = (__bf16*)qkv_c;  // alias: qkv region dead after proj GEMM

    mask_canon<<<32, 256, 0, stream>>>((const unsigned char*)kpm, msk, 8192);
    lens_kernel<<<4, 256, 0, stream>>>(msk, lens);
    tcvt<<<dim3(32, 32), 256, 0, stream>>>(wq, wqkvT, 1024, 1024);
    tcvt<<<dim3(32, 32), 256, 0, stream>>>(wk, wqkvT + 1024L * 1024, 1024, 1024);
    tcvt<<<dim3(32, 32), 256, 0, stream>>>(wv, wqkvT + 2048L * 1024, 1024, 1024);
    tcvt<<<dim3(32, 32), 256, 0, stream>>>(proj_w, wprojT, 1024, 1024);
    tcvt<<<dim3(128, 32), 256, 0, stream>>>(ff_w1, wff1T, 1024, 4096);
    tcvt<<<dim3(32, 128), 256, 0, stream>>>(ff_w2, wff2T, 4096, 1024);

    ln_kernel<<<8192, 256, 0, stream>>>(x, ln1w, ln1b, msk, h1);
    gemm_bt8<0><<<dim3(32, 12), 512, 0, stream>>>(h1, wqkvT, 1024, 3072, qkvb, nullptr);
    attn_kernel<<<dim3(64, 16), 256, 0, stream>>>(qkvb, lens, attb);
    gemm_bt8n<2><<<dim3(32, 8), 512, 0, stream>>>(attb, wprojT, 1024, 1024, x2, proj_b, x, nullptr);
    ln_kernel<<<8192, 256, 0, stream>>>(x2, ln2w, ln2b, msk, h2);
    gemm_bt8<1><<<dim3(32, 16), 512, 0, stream>>>(h2, wff1T, 1024, 4096, ffh, ff_b1);
    gemm_bt8n<3><<<dim3(32, 8), 512, 0, stream>>>(ffh, wff2T, 4096, 1024, (float*)d_out, ff_b2, x2, msk);
}

// Round 7
// 488.503 us; speedup vs baseline: 1.0507x; 1.0047x over previous
//
#include <hip/hip_runtime.h>
#include <math.h>

typedef float f32x4 __attribute__((ext_vector_type(4)));
typedef float f4 __attribute__((ext_vector_type(4)));
typedef __bf16 bf16x8 __attribute__((ext_vector_type(8)));
typedef __bf16 bf16x4 __attribute__((ext_vector_type(4)));

#define GLOBAL_AS __attribute__((address_space(1)))
#define LDS_AS __attribute__((address_space(3)))

// ---------------- mask canonicalization ----------------
__global__ __launch_bounds__(256) void mask_canon(const unsigned char* __restrict__ raw,
                                                  float* __restrict__ msk, int n) {
    int i = blockIdx.x * 256 + threadIdx.x;
    if (i >= n) return;
    unsigned int w0 = *(const unsigned int*)raw;
    float v;
    if (w0 == 0x01010101u)       v = raw[i] ? 1.f : 0.f;           // bool bytes
    else if (w0 == 0x3f800000u)  v = ((const float*)raw)[i];       // float32
    else                         v = ((const int*)raw)[i] ? 1.f : 0.f; // int32
    msk[i] = v;
}

// ---------------- per-batch valid length (right-padded prefix mask) ----------------
__global__ __launch_bounds__(256) void lens_kernel(const float* __restrict__ msk,
                                                   float* __restrict__ lens) {
    int b = blockIdx.x, tid = threadIdx.x;
    float s = 0.f;
    for (int i = tid; i < 2048; i += 256) s += msk[b * 2048 + i];
#pragma unroll
    for (int off = 1; off < 64; off <<= 1) s += __shfl_xor(s, off);
    __shared__ float red[4];
    int wave = tid >> 6, lane = tid & 63;
    if (lane == 0) red[wave] = s;
    __syncthreads();
    if (tid == 0) lens[b] = red[0] + red[1] + red[2] + red[3];
}

// ---------------- transpose + f32->bf16 convert: src[K][N] -> dst[N][K] ----------------
__global__ __launch_bounds__(256) void tcvt(const float* __restrict__ src,
                                            __bf16* __restrict__ dst, int K, int N) {
    __shared__ float tile[32][33];
    int n0 = blockIdx.x * 32, k0 = blockIdx.y * 32;
    int tx = threadIdx.x & 31, ty = threadIdx.x >> 5;  // ty 0..7
#pragma unroll
    for (int i = 0; i < 4; ++i)
        tile[ty + 8 * i][tx] = src[(long)(k0 + ty + 8 * i) * N + n0 + tx];
    __syncthreads();
#pragma unroll
    for (int i = 0; i < 4; ++i)
        dst[(long)(n0 + ty + 8 * i) * K + k0 + tx] = (__bf16)tile[tx][ty + 8 * i];
}

// ---------------- LayerNorm * mask -> bf16 ----------------
__global__ __launch_bounds__(256) void ln_kernel(const float* __restrict__ x,
                                                 const float* __restrict__ w,
                                                 const float* __restrict__ bsc,
                                                 const float* __restrict__ msk,
                                                 __bf16* __restrict__ out) {
    long row = blockIdx.x;
    int tid = threadIdx.x;
    f4 xv = *(const f4*)(x + row * 1024 + tid * 4);
    float s = xv[0] + xv[1] + xv[2] + xv[3];
    float sq = xv[0] * xv[0] + xv[1] * xv[1] + xv[2] * xv[2] + xv[3] * xv[3];
#pragma unroll
    for (int off = 1; off < 64; off <<= 1) {
        s += __shfl_xor(s, off);
        sq += __shfl_xor(sq, off);
    }
    __shared__ float red[2][4];
    int wave = tid >> 6, lane = tid & 63;
    if (lane == 0) { red[0][wave] = s; red[1][wave] = sq; }
    __syncthreads();
    s = red[0][0] + red[0][1] + red[0][2] + red[0][3];
    sq = red[1][0] + red[1][1] + red[1][2] + red[1][3];
    float mu = s * (1.0f / 1024.0f);
    float var = sq * (1.0f / 1024.0f) - mu * mu;
    float rs = rsqrtf(var + 1e-5f);
    float mv = msk[row];
    f4 wv = *(const f4*)(w + tid * 4);
    f4 bv = *(const f4*)(bsc + tid * 4);
    bf16x4 ov;
#pragma unroll
    for (int j = 0; j < 4; ++j)
        ov[j] = (__bf16)(((xv[j] - mu) * rs * wv[j] + bv[j]) * mv);
    *(bf16x4*)(out + row * 1024 + tid * 4) = ov;
}

// ======== shared phase-discipline asm helpers (m201 template) ========
#define BARRIER   __asm__ volatile("s_barrier" ::: "memory")
#define LGKM0     __asm__ volatile("s_waitcnt lgkmcnt(0)" ::: "memory")
#define PRIO1     __builtin_amdgcn_s_setprio(1)
#define PRIO0     __builtin_amdgcn_s_setprio(0)

// ---------------- bf16 GEMM, 256x256 tile, 8-phase, 2-tile-deep prefetch ----------------
// C = A[M,K]*B[N,K]^T. 512 thr = 8 waves (2M x 4N), per-wave C = 128x64.
// LDS [2 dbuf][2 half][128x64] per operand = 128 KiB.
// v7 change (deep prefetch): the ENTIRE tile t+2 is staged during tile t --
// B halves at p3 (B(d) reads complete at p2's lgkm0+barrier), A halves at p4
// (A(d) reads complete at p3's lgkm0+barrier). t+2's dbuf = (t+2)&1 = d = the
// CURRENT buffer, so region reuse is safe only after those read-completion
// barriers -- which is exactly where the staging sits. Tile t+1 was fully staged
// during t-1, so its loads have ~6 phases (~5000 cyc) of lead time; the only
// wait is vmcnt(8) at p4: steady queue = t+1(8 oldest) + t+2(8) -> retires
// exactly t+1, keeps t+2 in flight (T4: never drain mid-loop).
// Prologue: tiles 0+1 (16 loads) -> vmcnt(8). Tail: t+2>=NT -> vmcnt(0).
// EP: 0 = store bf16; 1 = +bias,relu -> bf16.
template <int EP>
__global__ __launch_bounds__(512, 2) void gemm_bt8(const __bf16* __restrict__ A,
                                                   const __bf16* __restrict__ B,
                                                   int K, int N, void* __restrict__ Cout,
                                                   const float* __restrict__ bias) {
    __shared__ __bf16 As[2][2][128 * 64];
    __shared__ __bf16 Bs[2][2][128 * 64];
    int tid = threadIdx.x;
    int wave = tid >> 6, lane = tid & 63;
    int l15 = lane & 15, quad = lane >> 4;
    int r8 = l15 & 7;
    int wm = wave >> 2, wn = wave & 3;
    long rowBase = (long)blockIdx.x * 256;
    long colBase = (long)blockIdx.y * 256;
    const __bf16* Ab = A + rowBase * K;
    const __bf16* Bb = B + colBase * K;
    int srow = lane >> 3;                 // 0..7
    int scol = ((lane & 7) ^ srow) * 8;   // pre-swizzled global col (elements)
    f32x4 acc[8][4] = {};

#define STGA(d_, h_, kt_)                                                                   \
    do {                                                                                    \
        _Pragma("unroll") for (int j = 0; j < 2; ++j) {                                     \
            const __bf16* g_ = Ab + (long)((h_) * 128 + wave * 16 + j * 8 + srow) * K +     \
                               (kt_) + scol;                                                \
            __builtin_amdgcn_global_load_lds(                                               \
                (const GLOBAL_AS void*)g_,                                                  \
                (LDS_AS void*)((char*)&As[d_][h_][0] + wave * 2048 + j * 1024), 16, 0, 0);  \
        }                                                                                   \
    } while (0)
#define STGB(d_, h_, kt_)                                                                   \
    do {                                                                                    \
        _Pragma("unroll") for (int j = 0; j < 2; ++j) {                                     \
            const __bf16* g_ = Bb + (long)((h_) * 128 + wave * 16 + j * 8 + srow) * K +     \
                               (kt_) + scol;                                                \
            __builtin_amdgcn_global_load_lds(                                               \
                (const GLOBAL_AS void*)g_,                                                  \
                (LDS_AS void*)((char*)&Bs[d_][h_][0] + wave * 2048 + j * 1024), 16, 0, 0);  \
        }                                                                                   \
    } while (0)
#define RDA(mh)                                                                      \
    do {                                                                             \
        _Pragma("unroll") for (int mi = 0; mi < 4; ++mi) {                           \
            int row_ = (mh) * 64 + mi * 16 + l15;                                    \
            af[mi][0] = *(const bf16x8*)(Ac + row_ * 64 + ((quad ^ r8) << 3));       \
            af[mi][1] = *(const bf16x8*)(Ac + row_ * 64 + (((4 + quad) ^ r8) << 3)); \
        }                                                                            \
    } while (0)
#define RDB(h)                                                                           \
    do {                                                                                 \
        _Pragma("unroll") for (int ni = 0; ni < 2; ++ni) {                               \
            int row_ = (wn & 1) * 64 + ((h) * 2 + ni) * 16 + l15;                        \
            bfr[h][ni][0] = *(const bf16x8*)(Bc + row_ * 64 + ((quad ^ r8) << 3));       \
            bfr[h][ni][1] = *(const bf16x8*)(Bc + row_ * 64 + (((4 + quad) ^ r8) << 3)); \
        }                                                                                \
    } while (0)
#define MM(mh, nh)                                                                          \
    do {                                                                                    \
        PRIO1;                                                                              \
        _Pragma("unroll") for (int mi = 0; mi < 4; ++mi) {                                  \
            _Pragma("unroll") for (int ni = 0; ni < 2; ++ni) {                              \
                acc[(mh) * 4 + mi][(nh) * 2 + ni] = __builtin_amdgcn_mfma_f32_16x16x32_bf16(\
                    af[mi][0], bfr[nh][ni][0], acc[(mh) * 4 + mi][(nh) * 2 + ni], 0, 0, 0); \
                acc[(mh) * 4 + mi][(nh) * 2 + ni] = __builtin_amdgcn_mfma_f32_16x16x32_bf16(\
                    af[mi][1], bfr[nh][ni][1], acc[(mh) * 4 + mi][(nh) * 2 + ni], 0, 0, 0); \
            }                                                                               \
        }                                                                                   \
        PRIO0;                                                                              \
    } while (0)

    const int NT = K >> 6;
    // prologue: tiles 0 and 1 fully staged (16 loads/thread)
    STGA(0, 0, 0); STGA(0, 1, 0); STGB(0, 0, 0); STGB(0, 1, 0);
    STGA(1, 0, 64); STGA(1, 1, 64); STGB(1, 0, 64); STGB(1, 1, 64);
    __asm__ volatile("s_waitcnt vmcnt(8)" ::: "memory");  // retire tile0, keep tile1
    BARRIER;

    bf16x8 af[4][2], bfr[2][2][2];
    int kt = 0;
    for (int t = 0; t < NT; ++t, kt += 64) {
        int d = t & 1;
        const __bf16* Ac = &As[d][wm][0];
        const __bf16* Bc = &Bs[d][wn >> 1][0];
        const bool haveT2 = (t + 2 < NT);
        // ---- p1 ----
        RDA(0); RDB(0);
        BARRIER; LGKM0;
        MM(0, 0);
        BARRIER;
        // ---- p2 ----
        RDB(1);
        BARRIER; LGKM0;
        MM(0, 1);
        BARRIER;
        // ---- p3 ----  (B(d) region free since p2's lgkm0+barrier)
        RDA(1);
        if (haveT2) { STGB(d, 0, kt + 128); STGB(d, 1, kt + 128); }
        BARRIER; LGKM0;
        MM(1, 1);
        BARRIER;
        // ---- p4 ----  (A(d) region free since p3's lgkm0+barrier)
        if (haveT2) {
            STGA(d, 0, kt + 128); STGA(d, 1, kt + 128);
            __asm__ volatile("s_waitcnt vmcnt(8)" ::: "memory");  // retire all of t+1
        } else {
            __asm__ volatile("s_waitcnt vmcnt(0)" ::: "memory");  // tail drain
        }
        BARRIER;
        MM(1, 0);
        BARRIER;
    }
#undef STGA
#undef STGB
#undef RDA
#undef RDB
#undef MM

#pragma unroll
    for (int mi = 0; mi < 8; ++mi) {
#pragma unroll
        for (int r = 0; r < 4; ++r) {
            long gr = rowBase + wm * 128 + mi * 16 + quad * 4 + r;
#pragma unroll
            for (int ni = 0; ni < 4; ++ni) {
                long gc = colBase + wn * 64 + ni * 16 + l15;
                float v = acc[mi][ni][r];
                if constexpr (EP == 0) {
                    ((__bf16*)Cout)[gr * N + gc] = (__bf16)v;
                } else {
                    v += bias[gc];
                    v = v > 0.f ? v : 0.f;
                    ((__bf16*)Cout)[gr * N + gc] = (__bf16)v;
                }
            }
        }
    }
}

// ---------------- bf16 GEMM, 256x128 tile, 8-phase, 2-tile-deep prefetch, f32 epilogue ----------------
// For N=1024 outputs (proj, ff2): grid (32,8) = 256 blocks = 1/CU. 8 waves 4M x 2N,
// per-wave C = 64x64. Same deep-prefetch ledger with 6 loads/tile (A=4, B=2):
// steady queue after p4 issue = t+1(6) + t+2(6) -> vmcnt(6).
// EP: 2 = +bias+resid -> f32; 3 = (+bias+resid)*msk[row] -> f32.
template <int EP>
__global__ __launch_bounds__(512, 2) void gemm_bt8n(const __bf16* __restrict__ A,
                                                    const __bf16* __restrict__ B,
                                                    int K, int N, void* __restrict__ Cout,
                                                    const float* __restrict__ bias,
                                                    const float* __restrict__ resid,
                                                    const float* __restrict__ mskp) {
    __shared__ __bf16 As2[2][2][128 * 64];
    __shared__ __bf16 Bs2[2][2][64 * 64];
    int tid = threadIdx.x;
    int wave = tid >> 6, lane = tid & 63;
    int l15 = lane & 15, quad = lane >> 4;
    int r8 = l15 & 7;
    int wm = wave >> 1, wn = wave & 1;   // 4M x 2N
    long rowBase = (long)blockIdx.x * 256;
    long colBase = (long)blockIdx.y * 128;
    const __bf16* Ab = A + rowBase * K;
    const __bf16* Bb = B + colBase * K;
    int srow = lane >> 3;                 // 0..7
    int scol = ((lane & 7) ^ srow) * 8;   // pre-swizzled global col
    f32x4 acc[4][4] = {};

#define NSTGA(d_, h_, kt_)                                                                  \
    do {                                                                                    \
        _Pragma("unroll") for (int j = 0; j < 2; ++j) {                                     \
            const __bf16* g_ = Ab + (long)((h_) * 128 + wave * 16 + j * 8 + srow) * K +     \
                               (kt_) + scol;                                                \
            __builtin_amdgcn_global_load_lds(                                               \
                (const GLOBAL_AS void*)g_,                                                  \
                (LDS_AS void*)((char*)&As2[d_][h_][0] + wave * 2048 + j * 1024), 16, 0, 0); \
        }                                                                                   \
    } while (0)
#define NSTGB(d_, h_, kt_)                                                                  \
    do {                                                                                    \
        const __bf16* g_ = Bb + (long)((h_) * 64 + wave * 8 + srow) * K + (kt_) + scol;     \
        __builtin_amdgcn_global_load_lds(                                                   \
            (const GLOBAL_AS void*)g_,                                                      \
            (LDS_AS void*)((char*)&Bs2[d_][h_][0] + wave * 1024), 16, 0, 0);                \
    } while (0)
#define NRA(H)                                                                           \
    do {                                                                                 \
        _Pragma("unroll") for (int mi = 0; mi < 2; ++mi) {                               \
            int row_ = (wm & 1) * 64 + ((H) * 2 + mi) * 16 + l15;                        \
            afr[H][mi][0] = *(const bf16x8*)(Ac + row_ * 64 + ((quad ^ r8) << 3));       \
            afr[H][mi][1] = *(const bf16x8*)(Ac + row_ * 64 + (((4 + quad) ^ r8) << 3)); \
        }                                                                                \
    } while (0)
#define NRB(H)                                                                            \
    do {                                                                                  \
        _Pragma("unroll") for (int ni = 0; ni < 2; ++ni) {                                \
            int row_ = ((H) * 2 + ni) * 16 + l15;                                         \
            bfr2[H][ni][0] = *(const bf16x8*)(Bc + row_ * 64 + ((quad ^ r8) << 3));       \
            bfr2[H][ni][1] = *(const bf16x8*)(Bc + row_ * 64 + (((4 + quad) ^ r8) << 3)); \
        }                                                                                 \
    } while (0)
#define NMM(AH, BH)                                                                          \
    do {                                                                                     \
        PRIO1;                                                                               \
        _Pragma("unroll") for (int mi = 0; mi < 2; ++mi) {                                   \
            _Pragma("unroll") for (int ni = 0; ni < 2; ++ni) {                               \
                acc[(AH) * 2 + mi][(BH) * 2 + ni] = __builtin_amdgcn_mfma_f32_16x16x32_bf16( \
                    afr[AH][mi][0], bfr2[BH][ni][0], acc[(AH) * 2 + mi][(BH) * 2 + ni], 0,   \
                    0, 0);                                                                   \
                acc[(AH) * 2 + mi][(BH) * 2 + ni] = __builtin_amdgcn_mfma_f32_16x16x32_bf16( \
                    afr[AH][mi][1], bfr2[BH][ni][1], acc[(AH) * 2 + mi][(BH) * 2 + ni], 0,   \
                    0, 0);                                                                   \
            }                                                                                \
        }                                                                                    \
        PRIO0;                                                                               \
    } while (0)

    const int NT = K >> 6;
    // prologue: tiles 0 and 1 fully staged (12 loads/thread)
    NSTGA(0, 0, 0); NSTGA(0, 1, 0); NSTGB(0, 0, 0); NSTGB(0, 1, 0);
    NSTGA(1, 0, 64); NSTGA(1, 1, 64); NSTGB(1, 0, 64); NSTGB(1, 1, 64);
    __asm__ volatile("s_waitcnt vmcnt(6)" ::: "memory");  // retire tile0, keep tile1
    BARRIER;

    bf16x8 afr[2][2][2], bfr2[2][2][2];
    int kt = 0;
    for (int t = 0; t < NT; ++t, kt += 64) {
        int d = t & 1;
        const __bf16* Ac = &As2[d][wm >> 1][0];
        const __bf16* Bc = &Bs2[d][wn][0];
        const bool haveT2 = (t + 2 < NT);
        // ---- p1 ----
        NRA(0); NRB(0);
        BARRIER; LGKM0;
        NMM(0, 0);
        BARRIER;
        // ---- p2 ----
        NRB(1);
        BARRIER; LGKM0;
        NMM(0, 1);
        BARRIER;
        // ---- p3 ----  (B(d) free since p2)
        NRA(1);
        if (haveT2) { NSTGB(d, 0, kt + 128); NSTGB(d, 1, kt + 128); }
        BARRIER; LGKM0;
        NMM(1, 1);
        BARRIER;
        // ---- p4 ----  (A(d) free since p3)
        if (haveT2) {
            NSTGA(d, 0, kt + 128); NSTGA(d, 1, kt + 128);
            __asm__ volatile("s_waitcnt vmcnt(6)" ::: "memory");  // retire all of t+1
        } else {
            __asm__ volatile("s_waitcnt vmcnt(0)" ::: "memory");
        }
        BARRIER;
        NMM(1, 0);
        BARRIER;
    }
#undef NSTGA
#undef NSTGB
#undef NRA
#undef NRB
#undef NMM

#pragma unroll
    for (int mi = 0; mi < 4; ++mi) {
#pragma unroll
        for (int r = 0; r < 4; ++r) {
            long gr = rowBase + wm * 64 + mi * 16 + quad * 4 + r;
#pragma unroll
            for (int ni = 0; ni < 4; ++ni) {
                long gc = colBase + wn * 64 + ni * 16 + l15;
                float v = acc[mi][ni][r];
                if constexpr (EP == 2) {
                    v += bias[gc] + resid[gr * N + gc];
                    ((float*)Cout)[gr * N + gc] = v;
                } else {
                    v = (v + bias[gc] + resid[gr * N + gc]) * mskp[gr];
                    ((float*)Cout)[gr * N + gc] = v;
                }
            }
        }
    }
}

// ---------------- fused flash attention v8 ----------------
#define SWIZ(row, d) ((row) * 64 + ((((d) >> 3) ^ ((row) & 7)) << 3) + ((d) & 7))
__global__ __launch_bounds__(256, 3) void attn_kernel(const __bf16* __restrict__ qkv,
                                                      const float* __restrict__ lens,
                                                      __bf16* __restrict__ att) {
    const int T = 2048, C3 = 3072;
    int bh = blockIdx.x;           // b*16 + h
    int qt = 15 - blockIdx.y;      // heavy tiles dispatch first
    int h = bh & 15, b = bh >> 4;
    int tid = threadIdx.x;
    int wave = tid >> 6, lane = tid & 63, l15 = lane & 15, quad = lane >> 4;

    __shared__ __bf16 Kl[64 * 64];      // [key][d], swizzled
    __shared__ __bf16 Vt[64 * 64];      // [d][key], swizzled
    __shared__ __bf16 Pl[4][32 * 64];   // per-wave [q][key], swizzled

    long rowB = (long)b * T;
    const __bf16* kbase = qkv + rowB * C3 + 1024 + h * 64;
    const __bf16* vbase = qkv + rowB * C3 + 2048 + h * 64;
    const float scale2 = (1.0f / 32.0f) * 1.44269504088896f;  // C^-0.5 * log2(e)

    int krow = tid >> 2, kd = (tid & 3) * 16;       // K staging: 4 lanes/row, 32B each
    int vk = (tid & 15) * 4, vd = (tid >> 4) * 4;   // V staging: 4 keys x 4 d per thread
    int vc8 = vk >> 3, vk7 = vk & 7;                // key chunk / in-chunk offset

    bf16x8 ones;
#pragma unroll
    for (int j = 0; j < 8; ++j) ones[j] = (__bf16)1.0f;

    __bf16* pw = &Pl[wave][0];
    int r8 = l15 & 7;  // row&7 for all frag reads (row = *16 + l15)

    int qbase = qt * 128;
    int wq0 = qbase + wave * 32;  // this wave's 32 q-rows

    bf16x8 qf[2][2];
#pragma unroll
    for (int g = 0; g < 2; ++g) {
        const __bf16* qptr = qkv + (rowB + wq0 + g * 16 + l15) * C3 + h * 64;
        qf[g][0] = *(const bf16x8*)(qptr + quad * 8);
        qf[g][1] = *(const bf16x8*)(qptr + 32 + quad * 8);
    }

    f32x4 o0[4] = {}, o1[4] = {};
    f32x4 lacc0 = {}, lacc1 = {};
    int nchunk = 2 * qt + 2;
    float len = lens[b];

    bf16x8 kpre0, kpre1;
    bf16x4 vpre[4];
    {
        const __bf16* kg = kbase + (long)krow * C3 + kd;
        kpre0 = *(const bf16x8*)kg;
        kpre1 = *(const bf16x8*)(kg + 8);
#pragma unroll
        for (int j = 0; j < 4; ++j)
            vpre[j] = *(const bf16x4*)(vbase + (long)(vk + j) * C3 + vd);
    }

    for (int c = 0; c < nchunk; ++c) {
        int k0 = c * 64;
        __asm__ volatile("s_barrier" ::: "memory");
        *(bf16x8*)(&Kl[SWIZ(krow, kd)]) = kpre0;
        *(bf16x8*)(&Kl[SWIZ(krow, kd + 8)]) = kpre1;
#pragma unroll
        for (int dd = 0; dd < 4; ++dd) {
            bf16x4 w = {vpre[0][dd], vpre[1][dd], vpre[2][dd], vpre[3][dd]};
            int d = vd + dd;
            *(bf16x4*)(&Vt[d * 64 + ((vc8 ^ (d & 7)) << 3) + vk7]) = w;
        }
        if (c + 1 < nchunk) {
            int k1 = k0 + 64;
            const __bf16* kg = kbase + (long)(k1 + krow) * C3 + kd;
            kpre0 = *(const bf16x8*)kg;
            kpre1 = *(const bf16x8*)(kg + 8);
#pragma unroll
            for (int j = 0; j < 4; ++j)
                vpre[j] = *(const bf16x4*)(vbase + (long)(k1 + vk + j) * C3 + vd);
        }
        __asm__ volatile("s_waitcnt lgkmcnt(0)\n\ts_barrier" ::: "memory");

        if (k0 <= wq0 + 31) {
            f32x4 s0[4] = {}, s1[4] = {};
#pragma unroll
            for (int n = 0; n < 4; ++n) {
                int row = n * 16 + l15;
                bf16x8 kb0 = *(const bf16x8*)(&Kl[row * 64 + ((quad ^ r8) << 3)]);
                bf16x8 kb1 = *(const bf16x8*)(&Kl[row * 64 + (((4 + quad) ^ r8) << 3)]);
                s0[n] = __builtin_amdgcn_mfma_f32_16x16x32_bf16(kb0, qf[0][0], s0[n], 0, 0, 0);
                s0[n] = __builtin_amdgcn_mfma_f32_16x16x32_bf16(kb1, qf[0][1], s0[n], 0, 0, 0);
                s1[n] = __builtin_amdgcn_mfma_f32_16x16x32_bf16(kb0, qf[1][0], s1[n], 0, 0, 0);
                s1[n] = __builtin_amdgcn_mfma_f32_16x16x32_bf16(kb1, qf[1][1], s1[n], 0, 0, 0);
            }

            bool needC = (k0 + 63 > wq0);
#pragma unroll
            for (int n = 0; n < 4; ++n) {
                int c8 = n * 2 + (quad >> 1);
                int sub = (quad & 1) * 4;
                bf16x4 w0, w1;
                if (!needC) {
#pragma unroll
                    for (int r = 0; r < 4; ++r) {
                        w0[r] = (__bf16)exp2f(s0[n][r] * scale2);
                        w1[r] = (__bf16)exp2f(s1[n][r] * scale2);
                    }
                } else {
                    int kg = k0 + n * 16 + quad * 4;
                    int qg0 = wq0 + l15, qg1 = wq0 + 16 + l15;
#pragma unroll
                    for (int r = 0; r < 4; ++r) {
                        w0[r] = (kg + r <= qg0) ? (__bf16)exp2f(s0[n][r] * scale2) : (__bf16)0.f;
                        w1[r] = (kg + r <= qg1) ? (__bf16)exp2f(s1[n][r] * scale2) : (__bf16)0.f;
                    }
                }
                int wbase = l15 * 64 + ((c8 ^ r8) << 3) + sub;
                *(bf16x4*)(pw + wbase) = w0;
                *(bf16x4*)(pw + 1024 + wbase) = w1;
            }
            __asm__ volatile("s_waitcnt lgkmcnt(0)" ::: "memory");

            bf16x8 pa00 = *(const bf16x8*)(pw + l15 * 64 + ((quad ^ r8) << 3));
            bf16x8 pa01 = *(const bf16x8*)(pw + l15 * 64 + (((4 + quad) ^ r8) << 3));
            bf16x8 pa10 = *(const bf16x8*)(pw + 1024 + l15 * 64 + ((quad ^ r8) << 3));
            bf16x8 pa11 = *(const bf16x8*)(pw + 1024 + l15 * 64 + (((4 + quad) ^ r8) << 3));
#pragma unroll
            for (int nd = 0; nd < 4; ++nd) {
                int row = nd * 16 + l15;
                bf16x8 vb0 = *(const bf16x8*)(&Vt[row * 64 + ((quad ^ r8) << 3)]);
                bf16x8 vb1 = *(const bf16x8*)(&Vt[row * 64 + (((4 + quad) ^ r8) << 3)]);
                o0[nd] = __builtin_amdgcn_mfma_f32_16x16x32_bf16(pa00, vb0, o0[nd], 0, 0, 0);
                o0[nd] = __builtin_amdgcn_mfma_f32_16x16x32_bf16(pa01, vb1, o0[nd], 0, 0, 0);
                o1[nd] = __builtin_amdgcn_mfma_f32_16x16x32_bf16(pa10, vb0, o1[nd], 0, 0, 0);
                o1[nd] = __builtin_amdgcn_mfma_f32_16x16x32_bf16(pa11, vb1, o1[nd], 0, 0, 0);
            }
            lacc0 = __builtin_amdgcn_mfma_f32_16x16x32_bf16(pa00, ones, lacc0, 0, 0, 0);
            lacc0 = __builtin_amdgcn_mfma_f32_16x16x32_bf16(pa01, ones, lacc0, 0, 0, 0);
            lacc1 = __builtin_amdgcn_mfma_f32_16x16x32_bf16(pa10, ones, lacc1, 0, 0, 0);
            lacc1 = __builtin_amdgcn_mfma_f32_16x16x32_bf16(pa11, ones, lacc1, 0, 0, 0);
        }
    }

#pragma unroll
    for (int r = 0; r < 4; ++r) {
        int q0g = wq0 + quad * 4 + r;
        float inv0 = 1.0f / (lacc0[r] - fmaxf(0.f, (float)(q0g + 1) - len));
        long orow0 = rowB + q0g;
        int q1g = q0g + 16;
        float inv1 = 1.0f / (lacc1[r] - fmaxf(0.f, (float)(q1g + 1) - len));
        long orow1 = rowB + q1g;
#pragma unroll
        for (int nd = 0; nd < 4; ++nd) {
            att[orow0 * 1024 + h * 64 + nd * 16 + l15] = (__bf16)(o0[nd][r] * inv0);
            att[orow1 * 1024 + h * 64 + nd * 16 + l15] = (__bf16)(o1[nd][r] * inv1);
        }
    }
}

// ---------------- launch ----------------
extern "C" void kernel_launch(void* const* d_in, const int* in_sizes, int n_in,
                              void* d_out, int out_size, void* d_ws, size_t ws_size,
                              hipStream_t stream) {
    const float* x      = (const float*)d_in[0];
    const void*  kpm    = d_in[1];
    const float* wq     = (const float*)d_in[2];
    const float* wk     = (const float*)d_in[3];
    const float* wv     = (const float*)d_in[4];
    const float* proj_w = (const float*)d_in[5];
    const float* proj_b = (const float*)d_in[6];
    const float* ff_w1  = (const float*)d_in[7];
    const float* ff_b1  = (const float*)d_in[8];
    const float* ff_w2  = (const float*)d_in[9];
    const float* ff_b2  = (const float*)d_in[10];
    const float* ln1w   = (const float*)d_in[11];
    const float* ln1b   = (const float*)d_in[12];
    const float* ln2w   = (const float*)d_in[13];
    const float* ln2b   = (const float*)d_in[14];

    char* ws = (char*)d_ws;
    size_t off = 0;
    auto take = [&](size_t bytes) -> char* {
        char* p = ws + off;
        off += (bytes + 255) & ~(size_t)255;
        return p;
    };
    float*  msk    = (float*)take(8192 * 4);
    float*  lens   = (float*)take(256);
    __bf16* wqkvT  = (__bf16*)take(3072L * 1024 * 2);
    __bf16* wprojT = (__bf16*)take(1024L * 1024 * 2);
    __bf16* wff1T  = (__bf16*)take(4096L * 1024 * 2);
    __bf16* wff2T  = (__bf16*)take(4096L * 1024 * 2);
    __bf16* h1     = (__bf16*)take(8192L * 1024 * 2);
    char*   qkv_c  = take(8192L * 3072 * 2);
    __bf16* qkvb   = (__bf16*)qkv_c;
    __bf16* attb   = (__bf16*)take(8192L * 1024 * 2);
    float*  x2     = (float*)take(8192L * 1024 * 4);
    __bf16* h2     = (__bf16*)take(8192L * 1024 * 2);
    __bf16* ffh    = (__bf16*)qkv_c;  // alias: qkv region dead after proj GEMM

    mask_canon<<<32, 256, 0, stream>>>((const unsigned char*)kpm, msk, 8192);
    lens_kernel<<<4, 256, 0, stream>>>(msk, lens);
    tcvt<<<dim3(32, 32), 256, 0, stream>>>(wq, wqkvT, 1024, 1024);
    tcvt<<<dim3(32, 32), 256, 0, stream>>>(wk, wqkvT + 1024L * 1024, 1024, 1024);
    tcvt<<<dim3(32, 32), 256, 0, stream>>>(wv, wqkvT + 2048L * 1024, 1024, 1024);
    tcvt<<<dim3(32, 32), 256, 0, stream>>>(proj_w, wprojT, 1024, 1024);
    tcvt<<<dim3(128, 32), 256, 0, stream>>>(ff_w1, wff1T, 1024, 4096);
    tcvt<<<dim3(32, 128), 256, 0, stream>>>(ff_w2, wff2T, 4096, 1024);

    ln_kernel<<<8192, 256, 0, stream>>>(x, ln1w, ln1b, msk, h1);
    gemm_bt8<0><<<dim3(32, 12), 512, 0, stream>>>(h1, wqkvT, 1024, 3072, qkvb, nullptr);
    attn_kernel<<<dim3(64, 16), 256, 0, stream>>>(qkvb, lens, attb);
    gemm_bt8n<2><<<dim3(32, 8), 512, 0, stream>>>(attb, wprojT, 1024, 1024, x2, proj_b, x, nullptr);
    ln_kernel<<<8192, 256, 0, stream>>>(x2, ln2w, ln2b, msk, h2);
    gemm_bt8<1><<<dim3(32, 16), 512, 0, stream>>>(h2, wff1T, 1024, 4096, ffh, ff_b1);
    gemm_bt8n<3><<<dim3(32, 8), 512, 0, stream>>>(ffh, wff2T, 4096, 1024, (float*)d_out, ff_b2, x2, msk);
}